// Round 13
// baseline (68.980 us; speedup 1.0000x reference)
//
#include <hip/hip_runtime.h>

// vol:  [B=8, D=64, H=128, W=128, C=2] f32
// flow: [B, D, H, W, 3] f32 (displacements)
// out:  [B, D, H, W, C] f32
//
// R13: 2 persistent blocks per CU (32 waves/CU, independent barrier groups
// overlap each other's phases). 512 blocks = 8b x 32h-tiles x 2w-halves.
// Per block: 4d x 4h x 64w voxels/iter (1 voxel/thread), 16 d-tile iters.
// LDS window: 11 planes x 12 rows x 72 cols x 2ch (channel-split) = 76,032 B
//   -> exactly 2 blocks/CU. Halos: d 4front/3back, h +-4, w +-4.
// Rolling stage: 4 new planes/iter, prefetched at top of iter
// (sched_barrier-pinned), ds_write between two barriers at iter end.
// |jitter| beyond halo (P ~ 4e-4 worst rows): exec-masked global fallback.

typedef float f32x4 __attribute__((ext_vector_type(4)));
typedef f32x4 __attribute__((aligned(8))) f32x4a;

#define WCOLS   72
#define PLANE_C (12 * WCOLS)      // 864 floats: one d-slot, one channel
#define NSLOT   11
#define CHOFF   (NSLOT * PLANE_C) // 9504: y-channel offset

__device__ __forceinline__ void sample_store(
    const float* __restrict__ vb, const float* lds, int db11,
    float f0, float f1, float f2,
    int d, int h, int w, int dbase, int hbase, int wbase,
    float* __restrict__ out, size_t vox)
{
    float cd = fminf(fmaxf((float)d + f0, 0.0f), 63.0f);
    float ch = fminf(fmaxf((float)h + f1, 0.0f), 127.0f);
    float cw = fminf(fmaxf((float)w + f2, 0.0f), 127.0f);
    int ld = (int)cd; ld = (ld > 62) ? 62 : ld;
    int lh = (int)ch; lh = (lh > 126) ? 126 : lh;
    int lw = (int)cw; lw = (lw > 126) ? 126 : lw;
    const float wd = cd - (float)ld;
    const float wh = ch - (float)lh;
    const float ww = cw - (float)lw;
    const int i_d = ld - dbase;   // LDS path needs <= 9  (plane ld+1 in window)
    const int i_h = lh - hbase;   // <= 10
    const int i_w = lw - wbase;   // <= 70

    float x00, x00r, x01, x01r, x10, x10r, x11, x11r;
    float y00, y00r, y01, y01r, y10, y10r, y11, y11r;
    if (__builtin_expect(((unsigned)i_d <= 9u) & ((unsigned)i_h <= 10u) &
                         ((unsigned)i_w <= 70u), 1)) {
        int m0 = db11 + i_d; if (m0 >= NSLOT) m0 -= NSLOT;
        int m1 = m0 + 1;     if (m1 == NSLOT) m1 = 0;
        const int ex0 = m0 * PLANE_C + i_h * WCOLS + i_w;
        const int ex1 = m1 * PLANE_C + i_h * WCOLS + i_w;
        x00 = lds[ex0];         x00r = lds[ex0 + 1];
        x01 = lds[ex0 + WCOLS]; x01r = lds[ex0 + WCOLS + 1];
        x10 = lds[ex1];         x10r = lds[ex1 + 1];
        x11 = lds[ex1 + WCOLS]; x11r = lds[ex1 + WCOLS + 1];
        y00 = lds[ex0 + CHOFF];         y00r = lds[ex0 + CHOFF + 1];
        y01 = lds[ex0 + CHOFF + WCOLS]; y01r = lds[ex0 + CHOFF + WCOLS + 1];
        y10 = lds[ex1 + CHOFF];         y10r = lds[ex1 + CHOFF + 1];
        y11 = lds[ex1 + CHOFF + WCOLS]; y11r = lds[ex1 + CHOFF + WCOLS + 1];
    } else {
        const int o = (ld << 15) + (lh << 8) + (lw << 1);
        const f32x4 a00 = *(const f32x4a*)(vb + o);
        const f32x4 a01 = *(const f32x4a*)(vb + o + 256);
        const f32x4 a10 = *(const f32x4a*)(vb + o + 32768);
        const f32x4 a11 = *(const f32x4a*)(vb + o + 33024);
        x00 = a00.x; y00 = a00.y; x00r = a00.z; y00r = a00.w;
        x01 = a01.x; y01 = a01.y; x01r = a01.z; y01r = a01.w;
        x10 = a10.x; y10 = a10.y; x10r = a10.z; y10r = a10.w;
        x11 = a11.x; y11 = a11.y; x11r = a11.z; y11r = a11.w;
    }

    const float wd0 = 1.0f - wd, wh0 = 1.0f - wh;
    const float ww1 = ww, ww0 = 1.0f - ww;
    const float w00 = wd0 * wh0, w01 = wd0 * wh;
    const float w10 = wd * wh0,  w11 = wd * wh;

    const float ox = (x00 * w00 + x01 * w01 + x10 * w10 + x11 * w11) * ww0
                   + (x00r * w00 + x01r * w01 + x10r * w10 + x11r * w11) * ww1;
    const float oy = (y00 * w00 + y01 * w01 + y10 * w10 + y11 * w11) * ww0
                   + (y00r * w00 + y01r * w01 + y10r * w10 + y11r * w11) * ww1;

    *(float2*)(out + vox * 2) = make_float2(ox, oy);
}

__global__ __launch_bounds__(1024, 8) void st_roll2_kernel(
    const float* __restrict__ vol,
    const float* __restrict__ flow,
    float* __restrict__ out)
{
    __shared__ float lds[2 * CHOFF];   // 76,032 B -> 2 blocks/CU

    const int t   = threadIdx.x;
    const int bid = blockIdx.x;        // b*64 + ht*2 + wh
    const int wh  = bid & 1;
    const int h0  = ((bid >> 1) & 31) << 2;
    const int b   = bid >> 6;
    const int w0  = wh << 6;
    const int hbase = h0 - 4;
    const int wbase = w0 - 4;

    const float* vb = vol + ((size_t)b << 21);

    // identity: 16 waves; wave-uniform (dr, hh); lanes span 64 consecutive w
    const int iw = t & 63;
    const int r  = t >> 6;          // 0..15
    const int dr = r >> 2;          // 0..3
    const int hh = h0 + (r & 3);
    const int w  = w0 + iw;

    // ---- initial stage: planes [-4..6] -> slots (i_d+7)%11; 4752 chunks ----
    for (int c = t; c < 11 * 12 * 36; c += 1024) {
        const int i_d = c / 432;                    // 12 rows x 36 chunks
        const int rem = c - i_d * 432;
        const int i_h = rem / 36;
        const int q   = rem - i_h * 36;
        const int gd  = max(i_d - 4, 0);
        const int gh  = min(max(hbase + i_h, 0), 127);
        int cc = wbase + (q << 1); cc = min(max(cc, 0), 126);
        const f32x4 v = *(const f32x4a*)(vb + ((((size_t)gd << 7) + gh) << 8) + (cc << 1));
        int sl = i_d + 7; if (sl >= NSLOT) sl -= NSLOT;
        const int e = sl * PLANE_C + i_h * WCOLS + (q << 1);
        *(float2*)&lds[e]         = make_float2(v.x, v.z);
        *(float2*)&lds[e + CHOFF] = make_float2(v.y, v.w);
    }

    // prologue flow (dt=0, d=dr)
    float cf0, cf1, cf2;
    {
        const size_t vox = ((((size_t)((b << 6) | dr) << 7) | hh) << 7) + w;
        const float* fp = flow + vox * 3;
        cf0 = fp[0]; cf1 = fp[1]; cf2 = fp[2];
    }
    __syncthreads();

    int db11 = 7;   // (dbase = -4) mod 11
    const bool second = (t < 704);   // waves 0..10: second staging chunk

    for (int dt = 0; dt < 16; ++dt) {
        const int d0    = dt << 2;
        const int dbase = d0 - 4;
        const int d     = d0 + dr;
        const size_t vox = ((((size_t)((b << 6) | d) << 7) | hh) << 7) + w;

        // ---- prefetch next-iter staging (2 f32x4) + flow (3 f32) ----
        f32x4 s0, s1; int le0 = 0, le1 = 0;
        float nf0, nf1, nf2;
        if (dt < 15) {
#define ISSUE_ST(C, VV, EE)                                                      \
            {                                                                    \
                const int c = (C);                                               \
                const int i_d4 = c / 432;                                        \
                const int rem  = c - i_d4 * 432;                                 \
                const int i_h  = rem / 36;                                       \
                const int q    = rem - i_h * 36;                                 \
                const int p    = d0 + 7 + i_d4;   /* new planes d0+7..d0+10 */   \
                const int gd   = (p > 63) ? 63 : p;                              \
                const int gh   = min(max(hbase + i_h, 0), 127);                  \
                int cc = wbase + (q << 1); cc = min(max(cc, 0), 126);            \
                VV = *(const f32x4a*)(vb + ((((size_t)gd << 7) + gh) << 8) + (cc << 1)); \
                int sl = db11 + i_d4; if (sl >= NSLOT) sl -= NSLOT;              \
                EE = sl * PLANE_C + i_h * WCOLS + (q << 1);                      \
            }
            ISSUE_ST(t, s0, le0)
            if (second) { ISSUE_ST(t + 1024, s1, le1) }
#undef ISSUE_ST
            const int dn = d + 4;
            const size_t voxn = ((((size_t)((b << 6) | dn) << 7) | hh) << 7) + w;
            const float* fp = flow + voxn * 3;
            nf0 = fp[0]; nf1 = fp[1]; nf2 = fp[2];
            __builtin_amdgcn_sched_barrier(0);   // pin prefetch above gather
        }

        // ---- gather current tile ----
        sample_store(vb, lds, db11, cf0, cf1, cf2, d, hh, w,
                     dbase, hbase, wbase, out, vox);

        // ---- rotate window ----
        if (dt < 15) {
            __syncthreads();                    // all gathers done
            *(float2*)&lds[le0]         = make_float2(s0.x, s0.z);
            *(float2*)&lds[le0 + CHOFF] = make_float2(s0.y, s0.w);
            if (second) {
                *(float2*)&lds[le1]         = make_float2(s1.x, s1.z);
                *(float2*)&lds[le1 + CHOFF] = make_float2(s1.y, s1.w);
            }
            __syncthreads();                    // new planes visible
            cf0 = nf0; cf1 = nf1; cf2 = nf2;
            db11 += 4; if (db11 >= NSLOT) db11 -= NSLOT;
        }
    }
}

extern "C" void kernel_launch(void* const* d_in, const int* in_sizes, int n_in,
                              void* d_out, int out_size, void* d_ws, size_t ws_size,
                              hipStream_t stream) {
    const float* vol  = (const float*)d_in[0];
    const float* flow = (const float*)d_in[1];
    float* out = (float*)d_out;

    // 8 batches x 32 h-tiles x 2 w-halves = 512 blocks (2 per CU)
    hipLaunchKernelGGL(st_roll2_kernel, dim3(512), dim3(1024), 0, stream,
                       vol, flow, out);
}